// Round 12
// baseline (380.543 us; speedup 1.0000x reference)
//
#include <hip/hip_runtime.h>
#include <math.h>

#define GG 512
#define TT 25
#define PP 10
#define MM 5
#define EE 32
#define HID 32
#define HH 128
#define NEDGE 40
#define NGRAPH (GG*TT)          // 12800
#define NTOT (GG*TT*PP)         // 128000

typedef __attribute__((ext_vector_type(8))) short short8v;
typedef __attribute__((ext_vector_type(4))) short short4v;
typedef __attribute__((ext_vector_type(4))) float f32x4;

// lstm A-panel LDS index: [s][ki<6][mt<2][lane<64][e<8] (shorts)
#define AIDX(s,ki,mt,l) (((((s)*6+(ki))*2+(mt))*64+(l))*8)
#define WB_PER_T 196608   // 2*6*32*64*8

// graph A-panel indices within U[10240] shorts (layouts used at disjoint times)
#define AXI(sp,mt,ki) ((((sp)*5+(mt))*2+(ki))*512)
#define AHI(sp,wh,mt) ((((sp)*2+(wh))*5+(mt))*512)
#define NWG 73728         // 36 units * 2(sp) * 2(nt) * 64 * 8

#define MFMA16(a,b,c) __builtin_amdgcn_mfma_f32_16x16x32_bf16(a,b,c,0,0,0)

__device__ __forceinline__ unsigned short f2bf(float x){
    unsigned u = __float_as_uint(x);
    u += 0x7fffu + ((u >> 16) & 1u);
    return (unsigned short)(u >> 16);
}
__device__ __forceinline__ float bf2f(unsigned short s){
    return __uint_as_float(((unsigned)s) << 16);
}
__device__ __forceinline__ float sigm(float x){ return 1.f/(1.f+__expf(-x)); }
__device__ __forceinline__ float tanh_fast(float x){
    float ax = fabsf(x);
    float e  = __expf(-2.f*ax);
    float t  = (1.f-e)/(1.f+e);
    return copysignf(t, x);
}

// ---------------------------------------------------------------------------
// Prep: LSTM weight frags + graph-GEMM B-fragments wG. (unchanged)
// ---------------------------------------------------------------------------
__global__ void prep_kernel(const float* __restrict__ W_ih, const float* __restrict__ W_hh,
                            const float* __restrict__ b_ih, const float* __restrict__ b_hh,
                            const float* __restrict__ Wb_pos, const float* __restrict__ Wb_neg,
                            const float* __restrict__ Wd_pos, const float* __restrict__ Wd_neg,
                            short* __restrict__ wB, float* __restrict__ wadd,
                            float* __restrict__ bsum, short* __restrict__ wG)
{
    const int NW = TT*WB_PER_T;          // 4,915,200
    const int NA = TT*2*512;             // 25,600
    const int NB = TT*512;               // 12,800
    const int total = NW + NA + NB + NWG;
    for (int idx = blockIdx.x*blockDim.x + threadIdx.x; idx < total;
         idx += gridDim.x*blockDim.x) {
        if (idx < NW) {
            int e  = idx & 7;
            int l  = (idx >> 3) & 63;
            int nt = (idx >> 9) & 31;
            int rest = idx >> 14;        // (t*2+s)*6 + ki
            int ki = rest % 6; rest /= 6;
            int s  = rest & 1;
            int t  = rest >> 1;
            int k  = ki*32 + (l >> 4)*8 + e;
            int n  = nt*16 + (l & 15);
            float wv = (k < 128) ? W_hh[(size_t)(t*512 + n)*128 + k]
                                 : W_ih[(size_t)(t*512 + n)*66 + (k - 128)];
            unsigned short hi = f2bf(wv);
            unsigned short outv = (s == 0) ? hi : f2bf(wv - bf2f(hi));
            wB[idx] = (short)outv;
        } else if (idx < NW + NA) {
            int i2 = idx - NW;
            int t = i2 / 1024, r = i2 % 1024;
            int cc = r >> 9, n = r & 511;
            wadd[i2] = W_ih[(size_t)(t*512 + n)*66 + 64 + cc];
        } else if (idx < NW + NA + NB) {
            int i3 = idx - NW - NA;
            bsum[i3] = b_ih[i3] + b_hh[i3];
        } else {
            int i4 = idx - NW - NA - NB;     // < 73728
            int e  = i4 & 7;
            int ll = (i4 >> 3) & 63;
            int nt = (i4 >> 9) & 1;
            int sp = (i4 >> 10) & 1;
            int u  = i4 >> 11;               // 0..35
            int n  = nt*16 + (ll & 15);
            int krow = (ll >> 4)*8 + e;
            float wv;
            if (u < 8) {
                int sgn = u >> 2, prod = (u >> 1) & 1, ki = u & 1;
                const float* Wb = sgn ? Wb_neg : Wb_pos;
                wv = Wb[(prod*64 + ki*32 + krow)*32 + n];
            } else {
                int v = u - 8;
                int wid = v % 7, sgn = (v / 7) & 1, lyr = v / 14;
                const float* Wd = (sgn ? Wd_neg : Wd_pos) + lyr*7168;
                wv = Wd[(wid*32 + krow)*32 + n];
            }
            unsigned short hi = f2bf(wv);
            wG[i4] = (sp == 0) ? (short)hi : (short)f2bf(wv - bf2f(hi));
        }
    }
}

// ---------------------------------------------------------------------------
// Graph kernel v8: same pipeline ordering as v7 but ROLLED — one textual
// bucket/store/apply instance each (software-pipelined q-loop). Cuts I$
// footprint ~6-8x and register hoisting pressure. 8 graphs / 256 threads.
// ---------------------------------------------------------------------------
__global__ __launch_bounds__(256) void graph_kernel(
    const float* __restrict__ x0,
    const float* __restrict__ bb_pos, const float* __restrict__ bb_neg,
    const float* __restrict__ bd_pos, const float* __restrict__ bd_neg,
    const short* __restrict__ wG,
    const int* __restrict__ pos_src, const int* __restrict__ pos_dst,
    const int* __restrict__ neg_src, const int* __restrict__ neg_dst,
    float* __restrict__ emb)
{
    __shared__ short U[10240];           // 20480 B: AX frags, then AH frags
    __shared__ float Yf[2][5760];        // 46080 B double-buffered [2sgn*80][36]
    __shared__ float Adj[8][4][10][10];  // 12800 B   total 79360 B

    const int tid = threadIdx.x;
    const int w   = tid >> 6;
    const int l   = tid & 63;
    const int li  = l & 15;
    const int lk  = l >> 4;
    const int s   = tid >> 7;            // output sign this thread owns
    const int rg  = (tid >> 3) & 15;     // row group (5 rows)
    const int c4  = tid & 7;             // 4-col group
    const int gq  = rg >> 1;             // graph (block-local)
    const int nbase = (rg & 1)*5;        // node base within graph

    // ---- stage x0 -> AX fragments (hi/lo bf16) ----
    for (int i = tid; i < 1280; i += 256) {
        int row = i >> 4, kq = i & 15;
        float4 f = ((const float4*)x0)[(size_t)blockIdx.x*1280 + i];
        int k0 = kq*4;
        int ln = (row & 15) + 16*((k0 >> 3) & 3);
        int ki = k0 >> 5, e0 = k0 & 7, mt = row >> 4;
        float vv[4] = {f.x, f.y, f.z, f.w};
        short4v hi4, lo4;
#pragma unroll
        for (int e2 = 0; e2 < 4; ++e2) {
            unsigned short h2 = f2bf(vv[e2]);
            hi4[e2] = (short)h2;
            lo4[e2] = (short)f2bf(vv[e2] - bf2f(h2));
        }
        *(short4v*)&U[AXI(0,mt,ki) + ln*8 + e0] = hi4;
        *(short4v*)&U[AXI(1,mt,ki) + ln*8 + e0] = lo4;
    }

    // ---- edges / counts / adjacency (overlaid in Yf[0], dead later) ----
    int*   Ses  = (int*)&Yf[0][0];
    float* Cm   = &Yf[0][0] + 1280;
    float* Scnt = &Yf[0][0] + 2880;
    for (int i = tid; i < 1280; i += 256) {
        int g = i / 160, r = i % 160, b = r / 40, e = r % 40;
        const int* p = (b==0)?pos_src:(b==1)?pos_dst:(b==2)?neg_src:neg_dst;
        Ses[i] = p[(blockIdx.x*8 + g)*40 + e];
    }
    for (int i = tid; i < 1600; i += 256) Cm[i] = 0.f;
    __syncthreads();
    for (int i = tid; i < 640; i += 256) {
        int g = i / 80, r = i % 80, si = r / 40, e = r % 40;
        int src = Ses[g*160 + (2*si)*40 + e];
        int dst = Ses[g*160 + (2*si+1)*40 + e];
        atomicAdd(&Cm[(g*2 + si)*100 + src*10 + dst], 1.f);
    }
    __syncthreads();
    for (int i = tid; i < 320; i += 256) {
        int g = i / 40, r = i % 40, b = r / 10, n = r % 10;
        int si = b >> 1, isCol = b & 1;
        float ssum = 0.f;
        for (int m = 0; m < 10; ++m)
            ssum += isCol ? Cm[(g*2+si)*100 + m*10 + n] : Cm[(g*2+si)*100 + n*10 + m];
        Scnt[i] = fmaxf(ssum, 1.f);
    }
    __syncthreads();
    for (int i = tid; i < 3200; i += 256) {
        int g = i / 400, r = i % 400, a = r / 100, rr = r % 100;
        int n = rr / 10, m = rr % 10;
        int si = a >> 1, isOut = a & 1;
        float cv = isOut ? Cm[(g*2+si)*100 + m*10 + n] : Cm[(g*2+si)*100 + n*10 + m];
        Adj[g][a][n][m] = cv / Scnt[g*40 + a*10 + n];
    }
    __syncthreads();   // Adj ready; Yf free

    f32x4 acc2[5];
    f32x4 cf[5];

    // single-instance helpers
    auto store_cf = [&](int buf) {
#pragma unroll
        for (int i = 0; i < 5; ++i) {
            int jid = w*5 + i;
            int sgn = (jid >= 10);
            int rem = jid - 10*sgn;
            int nt  = (rem >= 5);
            int mt2 = rem - 5*nt;
#pragma unroll
            for (int r = 0; r < 4; ++r)
                Yf[buf][(sgn*80 + mt2*16 + lk*4 + r)*36 + nt*16 + li] = cf[i][r];
        }
    };
    auto apply_adj = [&](int aIdx, int buf) {
#pragma unroll
        for (int m = 0; m < 10; ++m) {
            f32x4 y = *(const f32x4*)&Yf[buf][(s*80 + gq*10 + m)*36 + c4*4];
#pragma unroll
            for (int jj = 0; jj < 5; ++jj)
                acc2[jj] += Adj[gq][aIdx][nbase+jj][m] * y;
        }
    };
    auto apply_self = [&](int buf) {
#pragma unroll
        for (int jj = 0; jj < 5; ++jj)
            acc2[jj] += *(const f32x4*)&Yf[buf][(s*80 + rg*5 + jj)*36 + c4*4];
    };

    // =================== base layer (rolled, pipelined) ===================
    {
        const float* bb = s ? bb_neg : bb_pos;
        f32x4 b4 = *(const f32x4*)(bb + c4*4);
#pragma unroll
        for (int jj = 0; jj < 5; ++jj) acc2[jj] = b4;
    }
    for (int prod = 0; prod < 2; ++prod) {
#pragma unroll
        for (int i = 0; i < 5; ++i) {
            int jid = w*5 + i;
            int sgn = (jid >= 10);
            int rem = jid - 10*sgn;
            int nt  = (rem >= 5);
            int mt2 = rem - 5*nt;
            f32x4 c0 = {0.f,0.f,0.f,0.f};
#pragma unroll
            for (int ki = 0; ki < 2; ++ki) {
                short8v ah = *(const short8v*)&U[AXI(0,mt2,ki) + l*8];
                short8v al = *(const short8v*)&U[AXI(1,mt2,ki) + l*8];
                int u = sgn*4 + prod*2 + ki;
                const short* wp = wG + ((((size_t)u*2)*2 + nt)*64 + l)*8;
                short8v bh = *(const short8v*)wp;
                short8v bl = *(const short8v*)(wp + 1024);
                c0 = MFMA16(ah, bh, c0);
                c0 = MFMA16(ah, bl, c0);
                c0 = MFMA16(al, bh, c0);
            }
            cf[i] = c0;
        }
        if (prod == 0) {
            store_cf(0);
        } else {
            __syncthreads();        // Yf[0] ready
            apply_adj(2*s, 0);
            store_cf(1);
        }
    }
    __syncthreads();                // Yf[1] ready
    apply_self(1);
    // base epilogue: l2norm -> AH frags
#pragma unroll
    for (int jj = 0; jj < 5; ++jj) {
        f32x4 v = acc2[jj];
        float ss = v[0]*v[0] + v[1]*v[1] + v[2]*v[2] + v[3]*v[3];
        ss += __shfl_xor(ss,1); ss += __shfl_xor(ss,2); ss += __shfl_xor(ss,4);
        float rn = 1.f / fmaxf(sqrtf(ss), 1e-12f);
        v *= rn;
        int row = rg*5 + jj;
        int mt2 = row >> 4;
        int k0 = c4*4;
        int ln = (row & 15) + 16*((k0 >> 3) & 3);
        float vv[4] = {v[0], v[1], v[2], v[3]};
        short4v hi4, lo4;
#pragma unroll
        for (int e2 = 0; e2 < 4; ++e2) {
            unsigned short h2 = f2bf(vv[e2]);
            hi4[e2] = (short)h2;
            lo4[e2] = (short)f2bf(vv[e2] - bf2f(h2));
        }
        *(short4v*)&U[AHI(0,s,mt2) + ln*8 + (k0 & 7)] = hi4;
        *(short4v*)&U[AHI(1,s,mt2) + ln*8 + (k0 & 7)] = lo4;
    }
    __syncthreads();                // AH visible; Yf free

    // =================== two deep layers (rolled q-loop pipeline) ============
    for (int lyr = 0; lyr < 2; ++lyr) {
        {
            const float* bd = (s ? bd_neg : bd_pos) + lyr*32;
            f32x4 b4 = *(const f32x4*)(bd + c4*4);
#pragma unroll
            for (int jj = 0; jj < 5; ++jj) acc2[jj] = b4;
        }
        for (int q = 0; q <= 4; ++q) {
            // ---- bucket(q) -> cf (one textual instance) ----
            const int wid0 = (q == 4) ? 5 : q;
            const int rel0 = (q == 2 || q == 3) ? 1 : 0;
            const int two  = (q == 0 || q == 4);
            const int wid1 = (q == 0) ? 4 : 6;
#pragma unroll
            for (int i = 0; i < 5; ++i) {
                int jid = w*5 + i;
                int sgn = (jid >= 10);
                int rem = jid - 10*sgn;
                int nt  = (rem >= 5);
                int mt2 = rem - 5*nt;
                f32x4 c0 = {0.f,0.f,0.f,0.f};
                {
                    int wh = sgn ^ rel0;
                    int u = 8 + (lyr*2 + sgn)*7 + wid0;
                    short8v ah = *(const short8v*)&U[AHI(0,wh,mt2) + l*8];
                    short8v al = *(const short8v*)&U[AHI(1,wh,mt2) + l*8];
                    const short* wp = wG + ((((size_t)u*2)*2 + nt)*64 + l)*8;
                    short8v bh = *(const short8v*)wp;
                    short8v bl = *(const short8v*)(wp + 1024);
                    c0 = MFMA16(ah, bh, c0);
                    c0 = MFMA16(ah, bl, c0);
                    c0 = MFMA16(al, bh, c0);
                }
                if (two) {
                    int wh = sgn ^ 1;
                    int u = 8 + (lyr*2 + sgn)*7 + wid1;
                    short8v ah = *(const short8v*)&U[AHI(0,wh,mt2) + l*8];
                    short8v al = *(const short8v*)&U[AHI(1,wh,mt2) + l*8];
                    const short* wp = wG + ((((size_t)u*2)*2 + nt)*64 + l)*8;
                    short8v bh = *(const short8v*)wp;
                    short8v bl = *(const short8v*)(wp + 1024);
                    c0 = MFMA16(ah, bh, c0);
                    c0 = MFMA16(ah, bl, c0);
                    c0 = MFMA16(al, bh, c0);
                }
                cf[i] = c0;
            }
            if (q > 0) {
                __syncthreads();    // Yf[(q-1)&1] ready
                int qq = q - 1;
                int aIdx = (qq == 0) ? 2*s : (qq == 1) ? 2*s + 1
                         : (qq == 2) ? 2 - 2*s : 3 - 2*s;
                apply_adj(aIdx, qq & 1);
            }
            store_cf(q & 1);
        }
        __syncthreads();            // Yf[0] (bucket 4) ready
        apply_self(0);
        // epilogue: l2norm; write AH (lyr 0) or emb (lyr 1)
#pragma unroll
        for (int jj = 0; jj < 5; ++jj) {
            f32x4 v = acc2[jj];
            float ss = v[0]*v[0] + v[1]*v[1] + v[2]*v[2] + v[3]*v[3];
            ss += __shfl_xor(ss,1); ss += __shfl_xor(ss,2); ss += __shfl_xor(ss,4);
            float rn = 1.f / fmaxf(sqrtf(ss), 1e-12f);
            v *= rn;
            int row = rg*5 + jj;
            if (lyr == 0) {
                int mt2 = row >> 4;
                int k0 = c4*4;
                int ln = (row & 15) + 16*((k0 >> 3) & 3);
                float vv[4] = {v[0], v[1], v[2], v[3]};
                short4v hi4, lo4;
#pragma unroll
                for (int e2 = 0; e2 < 4; ++e2) {
                    unsigned short h2 = f2bf(vv[e2]);
                    hi4[e2] = (short)h2;
                    lo4[e2] = (short)f2bf(vv[e2] - bf2f(h2));
                }
                *(short4v*)&U[AHI(0,s,mt2) + ln*8 + (k0 & 7)] = hi4;
                *(short4v*)&U[AHI(1,s,mt2) + ln*8 + (k0 & 7)] = lo4;
            } else {
                *(f32x4*)&emb[((size_t)(blockIdx.x*80 + row))*64 + s*32 + c4*4] = v;
            }
        }
        __syncthreads();            // AH visible; Yf free for next layer
    }
}

// ---------------------------------------------------------------------------
// Persistent MFMA LSTM v2 (unchanged from r10 — known good).
// ---------------------------------------------------------------------------
#define LOADB(pt, pki, BH, BL)                                                 \
    {                                                                          \
        const short* wtp = wB + (size_t)(pt) * WB_PER_T;                       \
        _Pragma("unroll")                                                      \
        for (int g = 0; g < 4; ++g) {                                          \
            int nt = w + 8*g;                                                  \
            BH[g] = *(const short8v*)(wtp + (((size_t)(pki)*32 + nt)*64 + l)*8);      \
            BL[g] = *(const short8v*)(wtp + (((size_t)(6+(pki))*32 + nt)*64 + l)*8);  \
        }                                                                      \
    }

#define KI_STEP(ki, CH, CL, pt, pki, PH, PL)                                   \
    {                                                                          \
        short8v ah0 = *(const short8v*)&aP[AIDX(0,ki,0,l)];                    \
        short8v ah1 = *(const short8v*)&aP[AIDX(0,ki,1,l)];                    \
        short8v al0 = *(const short8v*)&aP[AIDX(1,ki,0,l)];                    \
        short8v al1 = *(const short8v*)&aP[AIDX(1,ki,1,l)];                    \
        LOADB(pt, pki, PH, PL)                                                 \
        _Pragma("unroll")                                                      \
        for (int g = 0; g < 4; ++g) {                                          \
            acc[0][g] = MFMA16(ah0, CH[g], acc[0][g]);                         \
            acc[0][g] = MFMA16(ah0, CL[g], acc[0][g]);                         \
            acc[0][g] = MFMA16(al0, CH[g], acc[0][g]);                         \
            acc[1][g] = MFMA16(ah1, CH[g], acc[1][g]);                         \
            acc[1][g] = MFMA16(ah1, CL[g], acc[1][g]);                         \
            acc[1][g] = MFMA16(al1, CH[g], acc[1][g]);                         \
        }                                                                      \
    }

__global__ __launch_bounds__(512) void lstm_mfma(
    const float* __restrict__ emb, const float* __restrict__ add_info,
    const short* __restrict__ wB, const float* __restrict__ wadd,
    const float* __restrict__ bsum, const float* __restrict__ hx0,
    const float* __restrict__ cx0, float* __restrict__ hbuf)
{
    __shared__ short aP[12288];
    __shared__ float Sadd[2][32][2];
    const int tid = threadIdx.x;
    const int w  = tid >> 6;
    const int l  = tid & 63;
    const int li = l & 15;
    const int lk = l >> 4;
    const int R0 = blockIdx.x * 32;

    {
        int row = tid >> 4, j0 = (tid & 15) * 8;
        const float* hp = hx0 + (size_t)(R0 + row)*128 + j0;
        float4 h0 = *(const float4*)hp;
        float4 h1 = *(const float4*)(hp + 4);
        float v[8] = {h0.x,h0.y,h0.z,h0.w,h1.x,h1.y,h1.z,h1.w};
        short8v hi, lo;
#pragma unroll
        for (int e = 0; e < 8; ++e) {
            unsigned short hs = f2bf(v[e]);
            hi[e] = (short)hs;
            lo[e] = (short)f2bf(v[e] - bf2f(hs));
        }
        int mt = row >> 4, ln = (row & 15) + 16*((j0 >> 3) & 3), ki = j0 >> 5;
        *(short8v*)&aP[AIDX(0,ki,mt,ln)] = hi;
        *(short8v*)&aP[AIDX(1,ki,mt,ln)] = lo;
    }
    {
        int row = tid >> 4, d0 = (tid & 15)*4;
        int R = R0 + row, g = R/10, p = R - 10*g;
        float4 f = *(const float4*)&emb[((size_t)(g*TT + 0)*PP + p)*64 + d0];
        int k0 = 128 + d0;
        int mt = row>>4, ln = (row&15) + 16*((k0>>3)&3), ki = k0>>5, e0 = k0&7;
        float v[4] = {f.x,f.y,f.z,f.w};
        short4v hi, lo;
#pragma unroll
        for (int e = 0; e < 4; ++e) {
            unsigned short hs = f2bf(v[e]);
            hi[e] = (short)hs;
            lo[e] = (short)f2bf(v[e] - bf2f(hs));
        }
        *(short4v*)&aP[AIDX(0,ki,mt,ln)+e0] = hi;
        *(short4v*)&aP[AIDX(1,ki,mt,ln)+e0] = lo;
    }
    if (tid < 64) {
        int row = tid >> 1, cc = tid & 1;
        int R = R0 + row, g = R/10, p = R - 10*g;
        Sadd[0][row][cc] = add_info[((size_t)(g*MM + 0)*PP + p)*2 + cc];
    }
    float c[2][4];
#pragma unroll
    for (int mt = 0; mt < 2; ++mt)
#pragma unroll
        for (int r = 0; r < 4; ++r) {
            int row = mt*16 + lk*4 + r;
            c[mt][r] = cx0[(size_t)(R0+row)*128 + 16*w + li];
        }

    short8v b0h[4], b0l[4], b1h[4], b1l[4], b2h[4], b2l[4];
    LOADB(0, 0, b0h, b0l)
    LOADB(0, 1, b1h, b1l)
    __syncthreads();

    for (int t = 0; t < TT; ++t) {
        const int tn = (t < TT-1) ? t+1 : t;
        float4 fnext;
        {
            int row = tid >> 4, d0 = (tid & 15)*4;
            int R = R0 + row, g = R/10, p = R - 10*g;
            fnext = *(const float4*)&emb[((size_t)(g*TT + tn)*PP + p)*64 + d0];
        }
        float adn0 = 0.f;
        if (tid < 64) {
            int rw = tid >> 1, cc = tid & 1;
            int R2 = R0 + rw, g2 = R2/10, p2 = R2 - 10*g2;
            adn0 = add_info[((size_t)(g2*MM + tn/MM)*PP + p2)*2 + cc];
        }
        float wa0[4], wa1[4];
#pragma unroll
        for (int g = 0; g < 4; ++g) {
            wa0[g] = wadd[(size_t)(t*2+0)*512 + 128*g + 16*w + li];
            wa1[g] = wadd[(size_t)(t*2+1)*512 + 128*g + 16*w + li];
        }

        f32x4 acc[2][4];
#pragma unroll
        for (int g = 0; g < 4; ++g) {
            float bs = bsum[t*512 + 128*g + 16*w + li];
            acc[0][g] = (f32x4){bs,bs,bs,bs};
            acc[1][g] = (f32x4){bs,bs,bs,bs};
        }

        KI_STEP(0, b0h, b0l, t,  2, b2h, b2l)
        KI_STEP(1, b1h, b1l, t,  3, b0h, b0l)
        KI_STEP(2, b2h, b2l, t,  4, b1h, b1l)
        KI_STEP(3, b0h, b0l, t,  5, b2h, b2l)
        KI_STEP(4, b1h, b1l, tn, 0, b0h, b0l)
        KI_STEP(5, b2h, b2l, tn, 1, b1h, b1l)
        __syncthreads();

        const int sb = t & 1;
        const int j  = 16*w + li;
        const int jsh = 16*((j >> 3) & 3);
        const int jki = j >> 5;
        const int je  = j & 7;
#pragma unroll
        for (int mt = 0; mt < 2; ++mt) {
#pragma unroll
            for (int r = 0; r < 4; ++r) {
                int row = mt*16 + lk*4 + r;
                float ad0 = Sadd[sb][row][0], ad1 = Sadd[sb][row][1];
                float v0 = acc[mt][0][r] + ad0*wa0[0] + ad1*wa1[0];
                float v1 = acc[mt][1][r] + ad0*wa0[1] + ad1*wa1[1];
                float v2 = acc[mt][2][r] + ad0*wa0[2] + ad1*wa1[2];
                float v3 = acc[mt][3][r] + ad0*wa0[3] + ad1*wa1[3];
                float iv = sigm(v0);
                float fv = sigm(v1);
                float gv = tanh_fast(v2);
                float ov = sigm(v3);
                float cn = fv*c[mt][r] + iv*gv;
                c[mt][r] = cn;
                float hv = ov*tanh_fast(cn);
                unsigned short hs = f2bf(hv);
                int ln = (row & 15) + jsh;
                aP[AIDX(0, jki, mt, ln) + je] = (short)hs;
                aP[AIDX(1, jki, mt, ln) + je] = (short)f2bf(hv - bf2f(hs));
                if (t == TT-1) hbuf[(size_t)(R0+row)*128 + j] = hv;
            }
        }
        if (t < TT-1) {
            int row = tid >> 4, d0 = (tid & 15)*4;
            int k0 = 128 + d0;
            int mt = row>>4, ln = (row&15) + 16*((k0>>3)&3), ki = k0>>5, e0 = k0&7;
            float v[4] = {fnext.x, fnext.y, fnext.z, fnext.w};
            short4v hi, lo;
#pragma unroll
            for (int e = 0; e < 4; ++e) {
                unsigned short hs = f2bf(v[e]);
                hi[e] = (short)hs;
                lo[e] = (short)f2bf(v[e] - bf2f(hs));
            }
            *(short4v*)&aP[AIDX(0,ki,mt,ln)+e0] = hi;
            *(short4v*)&aP[AIDX(1,ki,mt,ln)+e0] = lo;
            if (tid < 64) {
                int rw = tid >> 1, cc = tid & 1;
                Sadd[sb^1][rw][cc] = adn0;
            }
        }
        __syncthreads();
    }
}

// ---------------------------------------------------------------------------
// Final projection: out = h_last @ Wf + bf
// ---------------------------------------------------------------------------
__global__ __launch_bounds__(256) void final_proj(
    const float* __restrict__ hbuf, const float* __restrict__ Wf,
    const float* __restrict__ bf, float* __restrict__ out)
{
    __shared__ float wl[128*32];
    __shared__ float hl[64][128];
    const int tid = threadIdx.x;
    const int row0 = blockIdx.x * 64;
    for (int i = tid; i < 4096; i += 256) wl[i] = Wf[i];
    for (int i = tid; i < 8192; i += 256) hl[i>>7][i&127] = hbuf[row0*128 + i];
    __syncthreads();
    const int e  = tid & 31;
    const int rg = tid >> 5;
    float b = bf[e];
    float acc[8];
#pragma unroll
    for (int r=0;r<8;++r) acc[r] = b;
    for (int k = 0; k < 128; ++k) {
        float ww = wl[k*32 + e];
#pragma unroll
        for (int r=0;r<8;++r) acc[r] += hl[rg*8+r][k]*ww;
    }
#pragma unroll
    for (int r=0;r<8;++r) out[(row0 + rg*8 + r)*32 + e] = acc[r];
}

// ---------------------------------------------------------------------------
extern "C" void kernel_launch(void* const* d_in, const int* in_sizes, int n_in,
                              void* d_out, int out_size, void* d_ws, size_t ws_size,
                              hipStream_t stream)
{
    const float* x0       = (const float*)d_in[0];
    const float* add_info = (const float*)d_in[1];
    const float* Wb_pos   = (const float*)d_in[2];
    const float* bb_pos   = (const float*)d_in[3];
    const float* Wb_neg   = (const float*)d_in[4];
    const float* bb_neg   = (const float*)d_in[5];
    const float* Wd_pos   = (const float*)d_in[6];
    const float* bd_pos   = (const float*)d_in[7];
    const float* Wd_neg   = (const float*)d_in[8];
    const float* bd_neg   = (const float*)d_in[9];
    const float* W_ih     = (const float*)d_in[10];
    const float* W_hh     = (const float*)d_in[11];
    const float* b_ih     = (const float*)d_in[12];
    const float* b_hh     = (const float*)d_in[13];
    const float* hx0      = (const float*)d_in[14];
    const float* cx0      = (const float*)d_in[15];
    const float* Wf       = (const float*)d_in[16];
    const float* bf       = (const float*)d_in[17];
    const int*   pos_src  = (const int*)d_in[18];
    const int*   pos_dst  = (const int*)d_in[19];
    const int*   neg_src  = (const int*)d_in[20];
    const int*   neg_dst  = (const int*)d_in[21];

    float* ws    = (float*)d_ws;
    float* emb   = ws;                        // 8,192,000 f32
    float* hbuf  = emb   + 8192000;           //   655,360 f32
    float* bsumw = hbuf  + 655360;            //    12,800 f32
    float* waddw = bsumw + 12800;             //    25,600 f32
    short* wBw   = (short*)(waddw + 25600);   // 4,915,200 shorts
    short* wGw   = wBw + 4915200;             //    73,728 shorts (~45.6 MiB total)

    hipLaunchKernelGGL(prep_kernel, dim3(2048), dim3(256), 0, stream,
                       W_ih, W_hh, b_ih, b_hh, Wb_pos, Wb_neg, Wd_pos, Wd_neg,
                       wBw, waddw, bsumw, wGw);
    hipLaunchKernelGGL(graph_kernel, dim3(NGRAPH/8), dim3(256), 0, stream,
                       x0, bb_pos, bb_neg, bd_pos, bd_neg, wGw,
                       pos_src, pos_dst, neg_src, neg_dst, emb);
    hipLaunchKernelGGL(lstm_mfma, dim3(160), dim3(512), 0, stream,
                       emb, add_info, wBw, waddw, bsumw, hx0, cx0, hbuf);
    hipLaunchKernelGGL(final_proj, dim3(80), dim3(256), 0, stream,
                       hbuf, Wf, bf, (float*)d_out);
}

// Round 14
// 379.767 us; speedup vs baseline: 1.0020x; 1.0020x over previous
//
#include <hip/hip_runtime.h>
#include <math.h>

#define GG 512
#define TT 25
#define PP 10
#define MM 5
#define EE 32
#define HID 32
#define HH 128
#define NEDGE 40
#define NGRAPH (GG*TT)          // 12800
#define NTOT (GG*TT*PP)         // 128000

typedef __attribute__((ext_vector_type(8))) short short8v;
typedef __attribute__((ext_vector_type(4))) short short4v;
typedef __attribute__((ext_vector_type(4))) float f32x4;

// lstm A-panel LDS index: [s][ki<6][mt<2][lane<64][e<8] (shorts)
#define AIDX(s,ki,mt,l) (((((s)*6+(ki))*2+(mt))*64+(l))*8)
#define WB_PER_T 196608   // 2*6*32*64*8

// graph A-panel indices within U[10240] shorts (layouts used at disjoint times)
#define AXI(sp,mt,ki) ((((sp)*5+(mt))*2+(ki))*512)
#define AHI(sp,wh,mt) ((((sp)*2+(wh))*5+(mt))*512)
#define NWG 73728         // 36 units * 2(sp) * 2(nt) * 64 * 8

#define MFMA16(a,b,c) __builtin_amdgcn_mfma_f32_16x16x32_bf16(a,b,c,0,0,0)

__device__ __forceinline__ unsigned short f2bf(float x){
    unsigned u = __float_as_uint(x);
    u += 0x7fffu + ((u >> 16) & 1u);
    return (unsigned short)(u >> 16);
}
__device__ __forceinline__ float bf2f(unsigned short s){
    return __uint_as_float(((unsigned)s) << 16);
}
__device__ __forceinline__ float sigm(float x){ return 1.f/(1.f+__expf(-x)); }
__device__ __forceinline__ float tanh_fast(float x){
    float ax = fabsf(x);
    float e  = __expf(-2.f*ax);
    float t  = (1.f-e)/(1.f+e);
    return copysignf(t, x);
}

// ---------------------------------------------------------------------------
// Prep: LSTM weight frags + graph-GEMM B-fragments wG.
// ---------------------------------------------------------------------------
__global__ void prep_kernel(const float* __restrict__ W_ih, const float* __restrict__ W_hh,
                            const float* __restrict__ b_ih, const float* __restrict__ b_hh,
                            const float* __restrict__ Wb_pos, const float* __restrict__ Wb_neg,
                            const float* __restrict__ Wd_pos, const float* __restrict__ Wd_neg,
                            short* __restrict__ wB, float* __restrict__ wadd,
                            float* __restrict__ bsum, short* __restrict__ wG)
{
    const int NW = TT*WB_PER_T;          // 4,915,200
    const int NA = TT*2*512;             // 25,600
    const int NB = TT*512;               // 12,800
    const int total = NW + NA + NB + NWG;
    for (int idx = blockIdx.x*blockDim.x + threadIdx.x; idx < total;
         idx += gridDim.x*blockDim.x) {
        if (idx < NW) {
            int e  = idx & 7;
            int l  = (idx >> 3) & 63;
            int nt = (idx >> 9) & 31;
            int rest = idx >> 14;        // (t*2+s)*6 + ki
            int ki = rest % 6; rest /= 6;
            int s  = rest & 1;
            int t  = rest >> 1;
            int k  = ki*32 + (l >> 4)*8 + e;
            int n  = nt*16 + (l & 15);
            float wv = (k < 128) ? W_hh[(size_t)(t*512 + n)*128 + k]
                                 : W_ih[(size_t)(t*512 + n)*66 + (k - 128)];
            unsigned short hi = f2bf(wv);
            unsigned short outv = (s == 0) ? hi : f2bf(wv - bf2f(hi));
            wB[idx] = (short)outv;
        } else if (idx < NW + NA) {
            int i2 = idx - NW;
            int t = i2 / 1024, r = i2 % 1024;
            int cc = r >> 9, n = r & 511;
            wadd[i2] = W_ih[(size_t)(t*512 + n)*66 + 64 + cc];
        } else if (idx < NW + NA + NB) {
            int i3 = idx - NW - NA;
            bsum[i3] = b_ih[i3] + b_hh[i3];
        } else {
            int i4 = idx - NW - NA - NB;     // < 73728
            int e  = i4 & 7;
            int ll = (i4 >> 3) & 63;
            int nt = (i4 >> 9) & 1;
            int sp = (i4 >> 10) & 1;
            int u  = i4 >> 11;               // 0..35
            int n  = nt*16 + (ll & 15);
            int krow = (ll >> 4)*8 + e;
            float wv;
            if (u < 8) {
                int sgn = u >> 2, prod = (u >> 1) & 1, ki = u & 1;
                const float* Wb = sgn ? Wb_neg : Wb_pos;
                wv = Wb[(prod*64 + ki*32 + krow)*32 + n];
            } else {
                int v = u - 8;
                int wid = v % 7, sgn = (v / 7) & 1, lyr = v / 14;
                const float* Wd = (sgn ? Wd_neg : Wd_pos) + lyr*7168;
                wv = Wd[(wid*32 + krow)*32 + n];
            }
            unsigned short hi = f2bf(wv);
            wG[i4] = (sp == 0) ? (short)hi : (short)f2bf(wv - bf2f(hi));
        }
    }
}

// ---------------------------------------------------------------------------
// Graph kernel v8 (round-12 known-good): rolled pipelined buckets, 8 graphs
// per 256-thread block, double-buffered Yf.
// ---------------------------------------------------------------------------
__global__ __launch_bounds__(256) void graph_kernel(
    const float* __restrict__ x0,
    const float* __restrict__ bb_pos, const float* __restrict__ bb_neg,
    const float* __restrict__ bd_pos, const float* __restrict__ bd_neg,
    const short* __restrict__ wG,
    const int* __restrict__ pos_src, const int* __restrict__ pos_dst,
    const int* __restrict__ neg_src, const int* __restrict__ neg_dst,
    float* __restrict__ emb)
{
    __shared__ short U[10240];           // 20480 B: AX frags, then AH frags
    __shared__ float Yf[2][5760];        // 46080 B double-buffered [2sgn*80][36]
    __shared__ float Adj[8][4][10][10];  // 12800 B   total 79360 B

    const int tid = threadIdx.x;
    const int w   = tid >> 6;
    const int l   = tid & 63;
    const int li  = l & 15;
    const int lk  = l >> 4;
    const int s   = tid >> 7;            // output sign this thread owns
    const int rg  = (tid >> 3) & 15;     // row group (5 rows)
    const int c4  = tid & 7;             // 4-col group
    const int gq  = rg >> 1;             // graph (block-local)
    const int nbase = (rg & 1)*5;        // node base within graph

    // ---- stage x0 -> AX fragments (hi/lo bf16) ----
    for (int i = tid; i < 1280; i += 256) {
        int row = i >> 4, kq = i & 15;
        float4 f = ((const float4*)x0)[(size_t)blockIdx.x*1280 + i];
        int k0 = kq*4;
        int ln = (row & 15) + 16*((k0 >> 3) & 3);
        int ki = k0 >> 5, e0 = k0 & 7, mt = row >> 4;
        float vv[4] = {f.x, f.y, f.z, f.w};
        short4v hi4, lo4;
#pragma unroll
        for (int e2 = 0; e2 < 4; ++e2) {
            unsigned short h2 = f2bf(vv[e2]);
            hi4[e2] = (short)h2;
            lo4[e2] = (short)f2bf(vv[e2] - bf2f(h2));
        }
        *(short4v*)&U[AXI(0,mt,ki) + ln*8 + e0] = hi4;
        *(short4v*)&U[AXI(1,mt,ki) + ln*8 + e0] = lo4;
    }

    // ---- edges / counts / adjacency (overlaid in Yf[0], dead later) ----
    int*   Ses  = (int*)&Yf[0][0];
    float* Cm   = &Yf[0][0] + 1280;
    float* Scnt = &Yf[0][0] + 2880;
    for (int i = tid; i < 1280; i += 256) {
        int g = i / 160, r = i % 160, b = r / 40, e = r % 40;
        const int* p = (b==0)?pos_src:(b==1)?pos_dst:(b==2)?neg_src:neg_dst;
        Ses[i] = p[(blockIdx.x*8 + g)*40 + e];
    }
    for (int i = tid; i < 1600; i += 256) Cm[i] = 0.f;
    __syncthreads();
    for (int i = tid; i < 640; i += 256) {
        int g = i / 80, r = i % 80, si = r / 40, e = r % 40;
        int src = Ses[g*160 + (2*si)*40 + e];
        int dst = Ses[g*160 + (2*si+1)*40 + e];
        atomicAdd(&Cm[(g*2 + si)*100 + src*10 + dst], 1.f);
    }
    __syncthreads();
    for (int i = tid; i < 320; i += 256) {
        int g = i / 40, r = i % 40, b = r / 10, n = r % 10;
        int si = b >> 1, isCol = b & 1;
        float ssum = 0.f;
        for (int m = 0; m < 10; ++m)
            ssum += isCol ? Cm[(g*2+si)*100 + m*10 + n] : Cm[(g*2+si)*100 + n*10 + m];
        Scnt[i] = fmaxf(ssum, 1.f);
    }
    __syncthreads();
    for (int i = tid; i < 3200; i += 256) {
        int g = i / 400, r = i % 400, a = r / 100, rr = r % 100;
        int n = rr / 10, m = rr % 10;
        int si = a >> 1, isOut = a & 1;
        float cv = isOut ? Cm[(g*2+si)*100 + m*10 + n] : Cm[(g*2+si)*100 + n*10 + m];
        Adj[g][a][n][m] = cv / Scnt[g*40 + a*10 + n];
    }
    __syncthreads();   // Adj ready; Yf free

    f32x4 acc2[5];
    f32x4 cf[5];

    // single-instance helpers
    auto store_cf = [&](int buf) {
#pragma unroll
        for (int i = 0; i < 5; ++i) {
            int jid = w*5 + i;
            int sgn = (jid >= 10);
            int rem = jid - 10*sgn;
            int nt  = (rem >= 5);
            int mt2 = rem - 5*nt;
#pragma unroll
            for (int r = 0; r < 4; ++r)
                Yf[buf][(sgn*80 + mt2*16 + lk*4 + r)*36 + nt*16 + li] = cf[i][r];
        }
    };
    auto apply_adj = [&](int aIdx, int buf) {
#pragma unroll
        for (int m = 0; m < 10; ++m) {
            f32x4 y = *(const f32x4*)&Yf[buf][(s*80 + gq*10 + m)*36 + c4*4];
#pragma unroll
            for (int jj = 0; jj < 5; ++jj)
                acc2[jj] += Adj[gq][aIdx][nbase+jj][m] * y;
        }
    };
    auto apply_self = [&](int buf) {
#pragma unroll
        for (int jj = 0; jj < 5; ++jj)
            acc2[jj] += *(const f32x4*)&Yf[buf][(s*80 + rg*5 + jj)*36 + c4*4];
    };

    // =================== base layer (rolled, pipelined) ===================
    {
        const float* bb = s ? bb_neg : bb_pos;
        f32x4 b4 = *(const f32x4*)(bb + c4*4);
#pragma unroll
        for (int jj = 0; jj < 5; ++jj) acc2[jj] = b4;
    }
    for (int prod = 0; prod < 2; ++prod) {
#pragma unroll
        for (int i = 0; i < 5; ++i) {
            int jid = w*5 + i;
            int sgn = (jid >= 10);
            int rem = jid - 10*sgn;
            int nt  = (rem >= 5);
            int mt2 = rem - 5*nt;
            f32x4 c0 = {0.f,0.f,0.f,0.f};
#pragma unroll
            for (int ki = 0; ki < 2; ++ki) {
                short8v ah = *(const short8v*)&U[AXI(0,mt2,ki) + l*8];
                short8v al = *(const short8v*)&U[AXI(1,mt2,ki) + l*8];
                int u = sgn*4 + prod*2 + ki;
                const short* wp = wG + ((((size_t)u*2)*2 + nt)*64 + l)*8;
                short8v bh = *(const short8v*)wp;
                short8v bl = *(const short8v*)(wp + 1024);
                c0 = MFMA16(ah, bh, c0);
                c0 = MFMA16(ah, bl, c0);
                c0 = MFMA16(al, bh, c0);
            }
            cf[i] = c0;
        }
        if (prod == 0) {
            store_cf(0);
        } else {
            __syncthreads();        // Yf[0] ready
            apply_adj(2*s, 0);
            store_cf(1);
        }
    }
    __syncthreads();                // Yf[1] ready
    apply_self(1);
    // base epilogue: l2norm -> AH frags
#pragma unroll
    for (int jj = 0; jj < 5; ++jj) {
        f32x4 v = acc2[jj];
        float ss = v[0]*v[0] + v[1]*v[1] + v[2]*v[2] + v[3]*v[3];
        ss += __shfl_xor(ss,1); ss += __shfl_xor(ss,2); ss += __shfl_xor(ss,4);
        float rn = 1.f / fmaxf(sqrtf(ss), 1e-12f);
        v *= rn;
        int row = rg*5 + jj;
        int mt2 = row >> 4;
        int k0 = c4*4;
        int ln = (row & 15) + 16*((k0 >> 3) & 3);
        float vv[4] = {v[0], v[1], v[2], v[3]};
        short4v hi4, lo4;
#pragma unroll
        for (int e2 = 0; e2 < 4; ++e2) {
            unsigned short h2 = f2bf(vv[e2]);
            hi4[e2] = (short)h2;
            lo4[e2] = (short)f2bf(vv[e2] - bf2f(h2));
        }
        *(short4v*)&U[AHI(0,s,mt2) + ln*8 + (k0 & 7)] = hi4;
        *(short4v*)&U[AHI(1,s,mt2) + ln*8 + (k0 & 7)] = lo4;
    }
    __syncthreads();                // AH visible; Yf free

    // =================== two deep layers (rolled q-loop pipeline) ============
    for (int lyr = 0; lyr < 2; ++lyr) {
        {
            const float* bd = (s ? bd_neg : bd_pos) + lyr*32;
            f32x4 b4 = *(const f32x4*)(bd + c4*4);
#pragma unroll
            for (int jj = 0; jj < 5; ++jj) acc2[jj] = b4;
        }
        for (int q = 0; q <= 4; ++q) {
            // ---- bucket(q) -> cf (one textual instance) ----
            const int wid0 = (q == 4) ? 5 : q;
            const int rel0 = (q == 2 || q == 3) ? 1 : 0;
            const int two  = (q == 0 || q == 4);
            const int wid1 = (q == 0) ? 4 : 6;
#pragma unroll
            for (int i = 0; i < 5; ++i) {
                int jid = w*5 + i;
                int sgn = (jid >= 10);
                int rem = jid - 10*sgn;
                int nt  = (rem >= 5);
                int mt2 = rem - 5*nt;
                f32x4 c0 = {0.f,0.f,0.f,0.f};
                {
                    int wh = sgn ^ rel0;
                    int u = 8 + (lyr*2 + sgn)*7 + wid0;
                    short8v ah = *(const short8v*)&U[AHI(0,wh,mt2) + l*8];
                    short8v al = *(const short8v*)&U[AHI(1,wh,mt2) + l*8];
                    const short* wp = wG + ((((size_t)u*2)*2 + nt)*64 + l)*8;
                    short8v bh = *(const short8v*)wp;
                    short8v bl = *(const short8v*)(wp + 1024);
                    c0 = MFMA16(ah, bh, c0);
                    c0 = MFMA16(ah, bl, c0);
                    c0 = MFMA16(al, bh, c0);
                }
                if (two) {
                    int wh = sgn ^ 1;
                    int u = 8 + (lyr*2 + sgn)*7 + wid1;
                    short8v ah = *(const short8v*)&U[AHI(0,wh,mt2) + l*8];
                    short8v al = *(const short8v*)&U[AHI(1,wh,mt2) + l*8];
                    const short* wp = wG + ((((size_t)u*2)*2 + nt)*64 + l)*8;
                    short8v bh = *(const short8v*)wp;
                    short8v bl = *(const short8v*)(wp + 1024);
                    c0 = MFMA16(ah, bh, c0);
                    c0 = MFMA16(ah, bl, c0);
                    c0 = MFMA16(al, bh, c0);
                }
                cf[i] = c0;
            }
            if (q > 0) {
                __syncthreads();    // Yf[(q-1)&1] ready
                int qq = q - 1;
                int aIdx = (qq == 0) ? 2*s : (qq == 1) ? 2*s + 1
                         : (qq == 2) ? 2 - 2*s : 3 - 2*s;
                apply_adj(aIdx, qq & 1);
            }
            store_cf(q & 1);
        }
        __syncthreads();            // Yf[0] (bucket 4) ready
        apply_self(0);
        // epilogue: l2norm; write AH (lyr 0) or emb (lyr 1)
#pragma unroll
        for (int jj = 0; jj < 5; ++jj) {
            f32x4 v = acc2[jj];
            float ss = v[0]*v[0] + v[1]*v[1] + v[2]*v[2] + v[3]*v[3];
            ss += __shfl_xor(ss,1); ss += __shfl_xor(ss,2); ss += __shfl_xor(ss,4);
            float rn = 1.f / fmaxf(sqrtf(ss), 1e-12f);
            v *= rn;
            int row = rg*5 + jj;
            if (lyr == 0) {
                int mt2 = row >> 4;
                int k0 = c4*4;
                int ln = (row & 15) + 16*((k0 >> 3) & 3);
                float vv[4] = {v[0], v[1], v[2], v[3]};
                short4v hi4, lo4;
#pragma unroll
                for (int e2 = 0; e2 < 4; ++e2) {
                    unsigned short h2 = f2bf(vv[e2]);
                    hi4[e2] = (short)h2;
                    lo4[e2] = (short)f2bf(vv[e2] - bf2f(h2));
                }
                *(short4v*)&U[AHI(0,s,mt2) + ln*8 + (k0 & 7)] = hi4;
                *(short4v*)&U[AHI(1,s,mt2) + ln*8 + (k0 & 7)] = lo4;
            } else {
                *(f32x4*)&emb[((size_t)(blockIdx.x*80 + row))*64 + s*32 + c4*4] = v;
            }
        }
        __syncthreads();            // AH visible; Yf free for next layer
    }
}

// ---------------------------------------------------------------------------
// Persistent MFMA LSTM v2 (round-10 known-good).
// ---------------------------------------------------------------------------
#define LOADB(pt, pki, BH, BL)                                                 \
    {                                                                          \
        const short* wtp = wB + (size_t)(pt) * WB_PER_T;                       \
        _Pragma("unroll")                                                      \
        for (int g = 0; g < 4; ++g) {                                          \
            int nt = w + 8*g;                                                  \
            BH[g] = *(const short8v*)(wtp + (((size_t)(pki)*32 + nt)*64 + l)*8);      \
            BL[g] = *(const short8v*)(wtp + (((size_t)(6+(pki))*32 + nt)*64 + l)*8);  \
        }                                                                      \
    }

#define KI_STEP(ki, CH, CL, pt, pki, PH, PL)                                   \
    {                                                                          \
        short8v ah0 = *(const short8v*)&aP[AIDX(0,ki,0,l)];                    \
        short8v ah1 = *(const short8v*)&aP[AIDX(0,ki,1,l)];                    \
        short8v al0 = *(const short8v*)&aP[AIDX(1,ki,0,l)];                    \
        short8v al1 = *(const short8v*)&aP[AIDX(1,ki,1,l)];                    \
        LOADB(pt, pki, PH, PL)                                                 \
        _Pragma("unroll")                                                      \
        for (int g = 0; g < 4; ++g) {                                          \
            acc[0][g] = MFMA16(ah0, CH[g], acc[0][g]);                         \
            acc[0][g] = MFMA16(ah0, CL[g], acc[0][g]);                         \
            acc[0][g] = MFMA16(al0, CH[g], acc[0][g]);                         \
            acc[1][g] = MFMA16(ah1, CH[g], acc[1][g]);                         \
            acc[1][g] = MFMA16(ah1, CL[g], acc[1][g]);                         \
            acc[1][g] = MFMA16(al1, CH[g], acc[1][g]);                         \
        }                                                                      \
    }

__global__ __launch_bounds__(512) void lstm_mfma(
    const float* __restrict__ emb, const float* __restrict__ add_info,
    const short* __restrict__ wB, const float* __restrict__ wadd,
    const float* __restrict__ bsum, const float* __restrict__ hx0,
    const float* __restrict__ cx0, float* __restrict__ hbuf)
{
    __shared__ short aP[12288];
    __shared__ float Sadd[2][32][2];
    const int tid = threadIdx.x;
    const int w  = tid >> 6;
    const int l  = tid & 63;
    const int li = l & 15;
    const int lk = l >> 4;
    const int R0 = blockIdx.x * 32;

    {
        int row = tid >> 4, j0 = (tid & 15) * 8;
        const float* hp = hx0 + (size_t)(R0 + row)*128 + j0;
        float4 h0 = *(const float4*)hp;
        float4 h1 = *(const float4*)(hp + 4);
        float v[8] = {h0.x,h0.y,h0.z,h0.w,h1.x,h1.y,h1.z,h1.w};
        short8v hi, lo;
#pragma unroll
        for (int e = 0; e < 8; ++e) {
            unsigned short hs = f2bf(v[e]);
            hi[e] = (short)hs;
            lo[e] = (short)f2bf(v[e] - bf2f(hs));
        }
        int mt = row >> 4, ln = (row & 15) + 16*((j0 >> 3) & 3), ki = j0 >> 5;
        *(short8v*)&aP[AIDX(0,ki,mt,ln)] = hi;
        *(short8v*)&aP[AIDX(1,ki,mt,ln)] = lo;
    }
    {
        int row = tid >> 4, d0 = (tid & 15)*4;
        int R = R0 + row, g = R/10, p = R - 10*g;
        float4 f = *(const float4*)&emb[((size_t)(g*TT + 0)*PP + p)*64 + d0];
        int k0 = 128 + d0;
        int mt = row>>4, ln = (row&15) + 16*((k0>>3)&3), ki = k0>>5, e0 = k0&7;
        float v[4] = {f.x,f.y,f.z,f.w};
        short4v hi, lo;
#pragma unroll
        for (int e = 0; e < 4; ++e) {
            unsigned short hs = f2bf(v[e]);
            hi[e] = (short)hs;
            lo[e] = (short)f2bf(v[e] - bf2f(hs));
        }
        *(short4v*)&aP[AIDX(0,ki,mt,ln)+e0] = hi;
        *(short4v*)&aP[AIDX(1,ki,mt,ln)+e0] = lo;
    }
    if (tid < 64) {
        int row = tid >> 1, cc = tid & 1;
        int R = R0 + row, g = R/10, p = R - 10*g;
        Sadd[0][row][cc] = add_info[((size_t)(g*MM + 0)*PP + p)*2 + cc];
    }
    float c[2][4];
#pragma unroll
    for (int mt = 0; mt < 2; ++mt)
#pragma unroll
        for (int r = 0; r < 4; ++r) {
            int row = mt*16 + lk*4 + r;
            c[mt][r] = cx0[(size_t)(R0+row)*128 + 16*w + li];
        }

    short8v b0h[4], b0l[4], b1h[4], b1l[4], b2h[4], b2l[4];
    LOADB(0, 0, b0h, b0l)
    LOADB(0, 1, b1h, b1l)
    __syncthreads();

    for (int t = 0; t < TT; ++t) {
        const int tn = (t < TT-1) ? t+1 : t;
        float4 fnext;
        {
            int row = tid >> 4, d0 = (tid & 15)*4;
            int R = R0 + row, g = R/10, p = R - 10*g;
            fnext = *(const float4*)&emb[((size_t)(g*TT + tn)*PP + p)*64 + d0];
        }
        float adn0 = 0.f;
        if (tid < 64) {
            int rw = tid >> 1, cc = tid & 1;
            int R2 = R0 + rw, g2 = R2/10, p2 = R2 - 10*g2;
            adn0 = add_info[((size_t)(g2*MM + tn/MM)*PP + p2)*2 + cc];
        }
        float wa0[4], wa1[4];
#pragma unroll
        for (int g = 0; g < 4; ++g) {
            wa0[g] = wadd[(size_t)(t*2+0)*512 + 128*g + 16*w + li];
            wa1[g] = wadd[(size_t)(t*2+1)*512 + 128*g + 16*w + li];
        }

        f32x4 acc[2][4];
#pragma unroll
        for (int g = 0; g < 4; ++g) {
            float bs = bsum[t*512 + 128*g + 16*w + li];
            acc[0][g] = (f32x4){bs,bs,bs,bs};
            acc[1][g] = (f32x4){bs,bs,bs,bs};
        }

        KI_STEP(0, b0h, b0l, t,  2, b2h, b2l)
        KI_STEP(1, b1h, b1l, t,  3, b0h, b0l)
        KI_STEP(2, b2h, b2l, t,  4, b1h, b1l)
        KI_STEP(3, b0h, b0l, t,  5, b2h, b2l)
        KI_STEP(4, b1h, b1l, tn, 0, b0h, b0l)
        KI_STEP(5, b2h, b2l, tn, 1, b1h, b1l)
        __syncthreads();

        const int sb = t & 1;
        const int j  = 16*w + li;
        const int jsh = 16*((j >> 3) & 3);
        const int jki = j >> 5;
        const int je  = j & 7;
#pragma unroll
        for (int mt = 0; mt < 2; ++mt) {
#pragma unroll
            for (int r = 0; r < 4; ++r) {
                int row = mt*16 + lk*4 + r;
                float ad0 = Sadd[sb][row][0], ad1 = Sadd[sb][row][1];
                float v0 = acc[mt][0][r] + ad0*wa0[0] + ad1*wa1[0];
                float v1 = acc[mt][1][r] + ad0*wa0[1] + ad1*wa1[1];
                float v2 = acc[mt][2][r] + ad0*wa0[2] + ad1*wa1[2];
                float v3 = acc[mt][3][r] + ad0*wa0[3] + ad1*wa1[3];
                float iv = sigm(v0);
                float fv = sigm(v1);
                float gv = tanh_fast(v2);
                float ov = sigm(v3);
                float cn = fv*c[mt][r] + iv*gv;
                c[mt][r] = cn;
                float hv = ov*tanh_fast(cn);
                unsigned short hs = f2bf(hv);
                int ln = (row & 15) + jsh;
                aP[AIDX(0, jki, mt, ln) + je] = (short)hs;
                aP[AIDX(1, jki, mt, ln) + je] = (short)f2bf(hv - bf2f(hs));
                if (t == TT-1) hbuf[(size_t)(R0+row)*128 + j] = hv;
            }
        }
        if (t < TT-1) {
            int row = tid >> 4, d0 = (tid & 15)*4;
            int k0 = 128 + d0;
            int mt = row>>4, ln = (row&15) + 16*((k0>>3)&3), ki = k0>>5, e0 = k0&7;
            float v[4] = {fnext.x, fnext.y, fnext.z, fnext.w};
            short4v hi, lo;
#pragma unroll
            for (int e = 0; e < 4; ++e) {
                unsigned short hs = f2bf(v[e]);
                hi[e] = (short)hs;
                lo[e] = (short)f2bf(v[e] - bf2f(hs));
            }
            *(short4v*)&aP[AIDX(0,ki,mt,ln)+e0] = hi;
            *(short4v*)&aP[AIDX(1,ki,mt,ln)+e0] = lo;
            if (tid < 64) {
                int rw = tid >> 1, cc = tid & 1;
                Sadd[sb^1][rw][cc] = adn0;
            }
        }
        __syncthreads();
    }
}

// ---------------------------------------------------------------------------
// Final projection: out = h_last @ Wf + bf
// ---------------------------------------------------------------------------
__global__ __launch_bounds__(256) void final_proj(
    const float* __restrict__ hbuf, const float* __restrict__ Wf,
    const float* __restrict__ bf, float* __restrict__ out)
{
    __shared__ float wl[128*32];
    __shared__ float hl[64][128];
    const int tid = threadIdx.x;
    const int row0 = blockIdx.x * 64;
    for (int i = tid; i < 4096; i += 256) wl[i] = Wf[i];
    for (int i = tid; i < 8192; i += 256) hl[i>>7][i&127] = hbuf[row0*128 + i];
    __syncthreads();
    const int e  = tid & 31;
    const int rg = tid >> 5;
    float b = bf[e];
    float acc[8];
#pragma unroll
    for (int r=0;r<8;++r) acc[r] = b;
    for (int k = 0; k < 128; ++k) {
        float ww = wl[k*32 + e];
#pragma unroll
        for (int r=0;r<8;++r) acc[r] += hl[rg*8+r][k]*ww;
    }
#pragma unroll
    for (int r=0;r<8;++r) out[(row0 + rg*8 + r)*32 + e] = acc[r];
}

// ---------------------------------------------------------------------------
extern "C" void kernel_launch(void* const* d_in, const int* in_sizes, int n_in,
                              void* d_out, int out_size, void* d_ws, size_t ws_size,
                              hipStream_t stream)
{
    const float* x0       = (const float*)d_in[0];
    const float* add_info = (const float*)d_in[1];
    const float* Wb_pos   = (const float*)d_in[2];
    const float* bb_pos   = (const float*)d_in[3];
    const float* Wb_neg   = (const float*)d_in[4];
    const float* bb_neg   = (const float*)d_in[5];
    const float* Wd_pos   = (const float*)d_in[6];
    const float* bd_pos   = (const float*)d_in[7];
    const float* Wd_neg   = (const float*)d_in[8];
    const float* bd_neg   = (const float*)d_in[9];
    const float* W_ih     = (const float*)d_in[10];
    const float* W_hh     = (const float*)d_in[11];
    const float* b_ih     = (const float*)d_in[12];
    const float* b_hh     = (const float*)d_in[13];
    const float* hx0      = (const float*)d_in[14];
    const float* cx0      = (const float*)d_in[15];
    const float* Wf       = (const float*)d_in[16];
    const float* bf       = (const float*)d_in[17];
    const int*   pos_src  = (const int*)d_in[18];
    const int*   pos_dst  = (const int*)d_in[19];
    const int*   neg_src  = (const int*)d_in[20];
    const int*   neg_dst  = (const int*)d_in[21];

    float* ws    = (float*)d_ws;
    float* emb   = ws;                        // 8,192,000 f32
    float* hbuf  = emb   + 8192000;           //   655,360 f32
    float* bsumw = hbuf  + 655360;            //    12,800 f32
    float* waddw = bsumw + 12800;             //    25,600 f32
    short* wBw   = (short*)(waddw + 25600);   // 4,915,200 shorts
    short* wGw   = wBw + 4915200;             //    73,728 shorts (~45.6 MiB total)

    hipLaunchKernelGGL(prep_kernel, dim3(2048), dim3(256), 0, stream,
                       W_ih, W_hh, b_ih, b_hh, Wb_pos, Wb_neg, Wd_pos, Wd_neg,
                       wBw, waddw, bsumw, wGw);
    hipLaunchKernelGGL(graph_kernel, dim3(NGRAPH/8), dim3(256), 0, stream,
                       x0, bb_pos, bb_neg, bd_pos, bd_neg, wGw,
                       pos_src, pos_dst, neg_src, neg_dst, emb);
    hipLaunchKernelGGL(lstm_mfma, dim3(160), dim3(512), 0, stream,
                       emb, add_info, wBw, waddw, bsumw, hx0, cx0, hbuf);
    hipLaunchKernelGGL(final_proj, dim3(80), dim3(256), 0, stream,
                       hbuf, Wf, bf, (float*)d_out);
}